// Round 1
// baseline (474.050 us; speedup 1.0000x reference)
//
#include <hip/hip_runtime.h>
#include <hip/hip_bf16.h>

typedef __attribute__((ext_vector_type(8))) short short8;
typedef __attribute__((ext_vector_type(4))) float floatx4;

#define AS_STRIDE 72   // 64 cin + 8 pad -> 16B-aligned b128 reads, ~2-way banks (free)

// ---------------------------------------------------------------------------
// Kernel 1: kerT[n=s*128+co][k=(kh*3+kw)*64+ci] = bf16(mu + noise*exp(logstd))
// One block per (s, tap). Coalesced read (co fastest), LDS transpose,
// coalesced 8B writes (ci fastest).
// ---------------------------------------------------------------------------
__global__ void sample_kernels_k(const float* __restrict__ mu,
                                 const float* __restrict__ logstd,
                                 const float* __restrict__ noise,
                                 __hip_bfloat16* __restrict__ kerT) {
  __shared__ __hip_bfloat16 tile[128][68];  // [co][ci], pad 64->68
  const int s = blockIdx.x / 9;
  const int tap = blockIdx.x % 9;
  const float* mu_p = mu + tap * 8192;             // [ci][co] slice
  const float* ls_p = logstd + tap * 8192;
  const float* nz_p = noise + (s * 9 + tap) * 8192;
  for (int i = threadIdx.x; i < 8192; i += 256) {  // i = ci*128 + co
    int ci = i >> 7, co = i & 127;
    float v = mu_p[i] + nz_p[i] * expf(ls_p[i]);
    tile[co][ci] = __float2bfloat16(v);
  }
  __syncthreads();
  for (int i = threadIdx.x; i < 2048; i += 256) {  // 4 bf16 per thread-iter
    int co = i >> 4, c4 = (i & 15) << 2;
    uint2 v = *(const uint2*)&tile[co][c4];
    *(uint2*)(kerT + (size_t)(s * 128 + co) * 576 + tap * 64 + c4) = v;
  }
}

// ---------------------------------------------------------------------------
// Kernel 2: implicit-GEMM conv + ELU.
// Block = 128 pixels (2 rows x 64 w of one image) x 128 n-channels.
// 4 waves, each wave owns a 64x64 quadrant = 4x4 MFMA 16x16x32 bf16 tiles.
// A: x patch (4 rows x 66 cols x 64 cin) staged once in LDS as bf16.
// B: loaded straight from global (kerT is 1.18 MB -> L2-resident).
// Exactly one __syncthreads in the kernel.
// ---------------------------------------------------------------------------
__global__ __launch_bounds__(256, 4)
void conv_elu_k(const float* __restrict__ x,
                const __hip_bfloat16* __restrict__ kerT,
                float* __restrict__ out) {
  __shared__ __hip_bfloat16 As[4 * 66 * AS_STRIDE];  // 38016 B

  const int tid = threadIdx.x;
  const int lane15 = tid & 15;
  const int quad = (tid >> 4) & 3;
  const int wave = tid >> 6;
  const int n_tile = blockIdx.x;        // 0..7
  const int mt = blockIdx.y;            // 0..511
  const int b = mt >> 5;
  const int h0 = (mt & 31) << 1;        // first of 2 output rows

  // ---- Stage A: input rows h0-1 .. h0+2, cols -1..64, cin 0..63, bf16 ----
  const float* xb = x + (size_t)b * (64 * 64 * 64);
  for (int i = tid; i < 4 * 66 * 32; i += 256) {  // (r, j, cin-pair)
    int r = i / (66 * 32);
    int rem = i - r * (66 * 32);
    int j = rem >> 5;
    int p = rem & 31;
    int h_in = h0 + r - 1;
    int w_in = j - 1;
    float2 v = make_float2(0.f, 0.f);
    if ((unsigned)h_in < 64u && (unsigned)w_in < 64u)
      v = *(const float2*)(xb + (((h_in << 6) + w_in) << 6) + (p << 1));
    unsigned pk = (unsigned)__bfloat16_as_ushort(__float2bfloat16(v.x)) |
                  ((unsigned)__bfloat16_as_ushort(__float2bfloat16(v.y)) << 16);
    *(unsigned*)&As[(r * 66 + j) * AS_STRIDE + (p << 1)] = pk;
  }

  floatx4 acc[4][4] = {};

  const int row_sel = wave >> 1;        // which of the 2 output rows
  const int n_half = (wave & 1) << 6;   // 0 or 64 within the n-tile

  // B fragment base: lane holds B[k=quad*8+j][n=lane15] == kerT[n][k]
  const __hip_bfloat16* bBase =
      kerT + (size_t)(n_tile * 128 + n_half + lane15) * 576 + quad * 8;

  __syncthreads();  // A ready; no further barriers

  for (int tap = 0; tap < 9; ++tap) {
    const int kh = tap / 3;
    const int kw = tap - kh * 3;
    const __hip_bfloat16* aBase =
        As + ((row_sel + kh) * 66 + kw + lane15) * AS_STRIDE + quad * 8;
    const __hip_bfloat16* bTap = bBase + tap * 64;
#pragma unroll
    for (int khalf = 0; khalf < 2; ++khalf) {
      short8 af[4], bf[4];
#pragma unroll
      for (int ni = 0; ni < 4; ++ni)
        bf[ni] = *(const short8*)(bTap + ni * 16 * 576 + khalf * 32);
#pragma unroll
      for (int mi = 0; mi < 4; ++mi)
        af[mi] = *(const short8*)(aBase + mi * 16 * AS_STRIDE + khalf * 32);
#pragma unroll
      for (int mi = 0; mi < 4; ++mi)
#pragma unroll
        for (int ni = 0; ni < 4; ++ni)
          acc[mi][ni] = __builtin_amdgcn_mfma_f32_16x16x32_bf16(
              af[mi], bf[ni], acc[mi][ni], 0, 0, 0);
    }
  }

  // ---- Epilogue: ELU + store. D layout: row=quad*4+reg, col=lane15 ----
  const int h = h0 + row_sel;
  float* outp = out + (size_t)((b * 64 + h) * 64) * 1024 +
                (size_t)(n_tile * 128 + n_half + lane15);
#pragma unroll
  for (int mi = 0; mi < 4; ++mi) {
#pragma unroll
    for (int r = 0; r < 4; ++r) {
      int w = mi * 16 + quad * 4 + r;
      float* orow = outp + (size_t)w * 1024;
#pragma unroll
      for (int ni = 0; ni < 4; ++ni) {
        float v = acc[mi][ni][r];
        orow[ni * 16] = v > 0.f ? v : expm1f(v);
      }
    }
  }
}

extern "C" void kernel_launch(void* const* d_in, const int* in_sizes, int n_in,
                              void* d_out, int out_size, void* d_ws, size_t ws_size,
                              hipStream_t stream) {
  const float* x      = (const float*)d_in[0];
  const float* mu     = (const float*)d_in[1];
  const float* logstd = (const float*)d_in[2];
  const float* noise  = (const float*)d_in[3];
  float* out = (float*)d_out;
  __hip_bfloat16* kerT = (__hip_bfloat16*)d_ws;  // 1024 x 576 bf16 = 1.18 MB

  sample_kernels_k<<<72, 256, 0, stream>>>(mu, logstd, noise, kerT);
  conv_elu_k<<<dim3(8, 512), 256, 0, stream>>>(x, kerT, out);
}

// Round 2
// 381.251 us; speedup vs baseline: 1.2434x; 1.2434x over previous
//
#include <hip/hip_runtime.h>
#include <hip/hip_bf16.h>

typedef __attribute__((ext_vector_type(8))) short short8;
typedef __attribute__((ext_vector_type(4))) float floatx4;

#define AS_STRIDE 72   // 64 cin + 8 pad -> 16B-aligned b128 reads, 2-way banks (free)

// ---------------------------------------------------------------------------
// Kernel 1: emit sampled kernels directly in MFMA B-fragment order.
// kerF fragment index: (((s*18 + tap*2 + khalf)*8 + nz)*64 + lane), 8 bf16 each.
//   lane holds B[k = khalf*32 + (lane>>4)*8 + j][n = nz*16 + (lane&15)]
// so a wave's B-load in kernel 2 is one contiguous 1KB global_load_dwordx4.
// ---------------------------------------------------------------------------
__global__ void sample_kernels_k(const float* __restrict__ mu,
                                 const float* __restrict__ logstd,
                                 const float* __restrict__ noise,
                                 __hip_bfloat16* __restrict__ kerF) {
  const int s = blockIdx.x / 9, tap = blockIdx.x % 9;
  const float* mu_p = mu + tap * 8192;              // [ci][co]
  const float* ls_p = logstd + tap * 8192;
  const float* nz_p = noise + (s * 9 + tap) * 8192;
  for (int f = threadIdx.x; f < 1024; f += 256) {   // f = khalf*512 + nz*64 + lane
    int khalf = f >> 9;
    int nz = (f >> 6) & 7;
    int lane = f & 63;
    int co = nz * 16 + (lane & 15);
    int ci0 = khalf * 32 + ((lane >> 4) & 3) * 8;
    short8 frag;
#pragma unroll
    for (int j = 0; j < 8; ++j) {
      int idx = (ci0 + j) * 128 + co;
      float v = mu_p[idx] + nz_p[idx] * expf(ls_p[idx]);
      frag[j] = (short)__bfloat16_as_ushort(__float2bfloat16(v));
    }
    *(short8*)(kerF + ((size_t)((s * 18 + tap * 2 + khalf) * 8 + nz) * 64 + lane) * 8) = frag;
  }
}

// ---------------------------------------------------------------------------
// Kernel 2: implicit-GEMM conv + ELU.
// Block = 128 pixels (2 rows x 64 w) x 128 n. 4 waves, each a 64x64 quadrant
// (4x4 MFMA 16x16x32 bf16). A staged once in LDS (one barrier total).
// B read from global (L2-resident, fragment-ordered, 1KB/wave-load).
// Flat 18-step K-loop, fully unrolled, explicit 1-step register double-buffer.
// ---------------------------------------------------------------------------
__global__ __launch_bounds__(256, 4)
void conv_elu_k(const float* __restrict__ x,
                const __hip_bfloat16* __restrict__ kerF,
                float* __restrict__ out) {
  __shared__ __hip_bfloat16 As[4 * 66 * AS_STRIDE];  // 38016 B

  const int tid = threadIdx.x;
  const int lane = tid & 63;
  const int lane15 = tid & 15;
  const int quad = (tid >> 4) & 3;
  const int wave = tid >> 6;
  const int n_tile = blockIdx.x;        // 0..7  (= sample s)
  const int mt = blockIdx.y;            // 0..511
  const int b = mt >> 5;
  const int h0 = (mt & 31) << 1;

  // ---- Stage A: rows h0-1..h0+2, cols -1..64, cin 0..63 -> bf16 LDS ----
  const float* xb = x + (size_t)b * (64 * 64 * 64);
  for (int i = tid; i < 4 * 66 * 16; i += 256) {  // (r, j, cin-quad)
    int r = i / (66 * 16);
    int rem = i - r * (66 * 16);
    int j = rem >> 4;
    int p = rem & 15;                    // cin group of 4
    int h_in = h0 + r - 1;
    int w_in = j - 1;
    float4 v = make_float4(0.f, 0.f, 0.f, 0.f);
    if ((unsigned)h_in < 64u && (unsigned)w_in < 64u)
      v = *(const float4*)(xb + (((h_in << 6) + w_in) << 6) + (p << 2));
    ushort2 pk0 = {__bfloat16_as_ushort(__float2bfloat16(v.x)),
                   __bfloat16_as_ushort(__float2bfloat16(v.y))};
    ushort2 pk1 = {__bfloat16_as_ushort(__float2bfloat16(v.z)),
                   __bfloat16_as_ushort(__float2bfloat16(v.w))};
    *(ushort2*)&As[(r * 66 + j) * AS_STRIDE + (p << 2)] = pk0;
    *(ushort2*)&As[(r * 66 + j) * AS_STRIDE + (p << 2) + 2] = pk1;
  }

  floatx4 acc[4][4] = {};

  const int row_sel = wave >> 1;         // which of the 2 output rows
  const int nz0 = (wave & 1) << 2;       // fragment nz base (0 or 4)
  const __hip_bfloat16* bTile = kerF + (size_t)n_tile * 18 * 8 * 64 * 8;

  __syncthreads();  // A ready; no further barriers

  short8 aC[4], bC[4], aN[4], bN[4];

  auto loadB = [&](short8* dst, int ks) {
#pragma unroll
    for (int ni = 0; ni < 4; ++ni)
      dst[ni] = *(const short8*)(bTile + ((size_t)(ks * 8 + nz0 + ni) * 64 + lane) * 8);
  };
  auto loadA = [&](short8* dst, int ks) {
    const int tap = ks >> 1, khalf = ks & 1;
    const int kh = tap / 3, kw = tap - kh * 3;
    const __hip_bfloat16* aBase =
        As + ((row_sel + kh) * 66 + kw + lane15) * AS_STRIDE + quad * 8 + khalf * 32;
#pragma unroll
    for (int mi = 0; mi < 4; ++mi)
      dst[mi] = *(const short8*)(aBase + mi * 16 * AS_STRIDE);
  };

  loadB(bC, 0);
  loadA(aC, 0);
#pragma unroll
  for (int ks = 0; ks < 18; ++ks) {
    if (ks < 17) {
      loadB(bN, ks + 1);
      loadA(aN, ks + 1);
    }
#pragma unroll
    for (int mi = 0; mi < 4; ++mi)
#pragma unroll
      for (int ni = 0; ni < 4; ++ni)
        acc[mi][ni] = __builtin_amdgcn_mfma_f32_16x16x32_bf16(
            aC[mi], bC[ni], acc[mi][ni], 0, 0, 0);
#pragma unroll
    for (int r = 0; r < 4; ++r) { aC[r] = aN[r]; bC[r] = bN[r]; }
  }

  // ---- Epilogue: ELU + store. D layout: row=quad*4+reg, col=lane15 ----
  const int h = h0 + row_sel;
  float* outp = out + (size_t)((b * 64 + h) * 64) * 1024 +
                (size_t)(n_tile * 128 + (nz0 << 4) + lane15);
#pragma unroll
  for (int mi = 0; mi < 4; ++mi) {
#pragma unroll
    for (int r = 0; r < 4; ++r) {
      int w = mi * 16 + quad * 4 + r;
      float* orow = outp + (size_t)w * 1024;
#pragma unroll
      for (int ni = 0; ni < 4; ++ni) {
        float v = acc[mi][ni][r];
        orow[ni * 16] = v > 0.f ? v : expm1f(v);
      }
    }
  }
}

extern "C" void kernel_launch(void* const* d_in, const int* in_sizes, int n_in,
                              void* d_out, int out_size, void* d_ws, size_t ws_size,
                              hipStream_t stream) {
  const float* x      = (const float*)d_in[0];
  const float* mu     = (const float*)d_in[1];
  const float* logstd = (const float*)d_in[2];
  const float* noise  = (const float*)d_in[3];
  float* out = (float*)d_out;
  __hip_bfloat16* kerF = (__hip_bfloat16*)d_ws;  // 1024*576 bf16 = 1.18 MB, fragment order

  sample_kernels_k<<<72, 256, 0, stream>>>(mu, logstd, noise, kerF);
  conv_elu_k<<<dim3(8, 512), 256, 0, stream>>>(x, kerF, out);
}

// Round 4
// 342.773 us; speedup vs baseline: 1.3830x; 1.1123x over previous
//
#include <hip/hip_runtime.h>
#include <hip/hip_bf16.h>

typedef __attribute__((ext_vector_type(8))) short short8;
typedef __attribute__((ext_vector_type(8))) unsigned short ushort8;
typedef __attribute__((ext_vector_type(4))) float floatx4;

#define AS_STRIDE 72   // 64 cin + 8 pad -> 16B-aligned b128, 2-way banks (free)

// ws layout: [0, 1179648) kerF (1024x576 bf16, fragment order)
//            [1179648, +8921088) xpad bf16 [16][66][66][64], zero borders
#define KERF_BYTES (1024 * 576 * 2)

// ---------------------------------------------------------------------------
// Prep kernel (fused):
//  blocks 0..71   : sample kernels -> kerF in MFMA B-fragment order.
//  blocks 72..2249: build xpad = bf16(x) zero-padded to 66x66 spatially.
// ---------------------------------------------------------------------------
__global__ void prep_k(const float* __restrict__ x,
                       const float* __restrict__ mu,
                       const float* __restrict__ logstd,
                       const float* __restrict__ noise,
                       __hip_bfloat16* __restrict__ kerF,
                       __hip_bfloat16* __restrict__ xpad) {
  const int bx = blockIdx.x;
  const int tid = threadIdx.x;
  if (bx >= 72) {
    // ---- xpad: i indexes 8-channel segments of padded rows ----
    int i = (bx - 72) * 256 + tid;            // < 557568 = 16*66*66*8
    int row = i >> 3, seg = i & 7;            // row < 69696
    int b = row / 4356;                       // 66*66
    int rem = row - b * 4356;
    int hp = rem / 66, wp = rem - (rem / 66) * 66;
    int h = hp - 1, w = wp - 1;
    ushort8 val = {0, 0, 0, 0, 0, 0, 0, 0};
    if ((unsigned)h < 64u && (unsigned)w < 64u) {
      const float* src = x + ((((size_t)b * 64 + h) * 64 + w) << 6) + (seg << 3);
      float4 v0 = *(const float4*)src;
      float4 v1 = *(const float4*)(src + 4);
      val[0] = __bfloat16_as_ushort(__float2bfloat16(v0.x));
      val[1] = __bfloat16_as_ushort(__float2bfloat16(v0.y));
      val[2] = __bfloat16_as_ushort(__float2bfloat16(v0.z));
      val[3] = __bfloat16_as_ushort(__float2bfloat16(v0.w));
      val[4] = __bfloat16_as_ushort(__float2bfloat16(v1.x));
      val[5] = __bfloat16_as_ushort(__float2bfloat16(v1.y));
      val[6] = __bfloat16_as_ushort(__float2bfloat16(v1.z));
      val[7] = __bfloat16_as_ushort(__float2bfloat16(v1.w));
    }
    *(ushort8*)(xpad + ((size_t)row << 6) + (seg << 3)) = val;
  } else {
    // ---- sample: kerF[((s*18 + tap*2 + khalf)*8 + nz)*64 + lane][8] ----
    // lane holds B[k=khalf*32+((lane>>4)&3)*8+j][n=nz*16+(lane&15)]
    const int s = bx / 9, tap = bx % 9;
    const float* mu_p = mu + tap * 8192;      // [ci][co]
    const float* ls_p = logstd + tap * 8192;
    const float* nz_p = noise + (s * 9 + tap) * 8192;
    for (int f = tid; f < 1024; f += 256) {   // f = khalf*512 + nz*64 + lane
      int khalf = f >> 9;
      int nz = (f >> 6) & 7;
      int lane = f & 63;
      int co = nz * 16 + (lane & 15);
      int ci0 = khalf * 32 + ((lane >> 4) & 3) * 8;
      short8 frag;
#pragma unroll
      for (int j = 0; j < 8; ++j) {
        int idx = (ci0 + j) * 128 + co;
        float v = mu_p[idx] + nz_p[idx] * expf(ls_p[idx]);
        frag[j] = (short)__bfloat16_as_ushort(__float2bfloat16(v));
      }
      *(short8*)(kerF + ((size_t)((s * 18 + tap * 2 + khalf) * 8 + nz) * 64 + lane) * 8) = frag;
    }
  }
}

// ---------------------------------------------------------------------------
// Conv + ELU, implicit GEMM. Block = 128 pixels (2 rows x 64 w) x 128 n.
// 4 waves x (4x4 MFMA 16x16x32 bf16). A staged once (bf16 source, one
// barrier total); B from global (L2-resident, fragment-ordered).
// K-loop fully unrolled, 2-deep B prefetch, 1-deep A prefetch.
// ---------------------------------------------------------------------------
__global__ __launch_bounds__(256, 4)
void conv_elu_k(const __hip_bfloat16* __restrict__ xpad,
                const __hip_bfloat16* __restrict__ kerF,
                float* __restrict__ out) {
  __shared__ __hip_bfloat16 As[4 * 66 * AS_STRIDE];  // 38016 B

  const int tid = threadIdx.x;
  const int lane = tid & 63;
  const int lane15 = tid & 15;
  const int quad = (tid >> 4) & 3;
  const int wave = tid >> 6;
  const int n_tile = blockIdx.x;        // 0..7  (= sample s)
  const int mt = blockIdx.y;            // 0..511
  const int b = mt >> 5;
  const int h0 = (mt & 31) << 1;

  // ---- Stage A: xpad rows h0..h0+3 (contiguous), 16B loads, no branches ----
  const __hip_bfloat16* xbase = xpad + (((size_t)(b * 66 + h0) * 66) << 6);
  for (int c = tid; c < 2112; c += 256) {        // 2112 x 16B = 33792 B
    ushort8 v = *(const ushort8*)(xbase + ((size_t)c << 3));
    int r = c / 528;                             // 528 chunks per padded row
    int cc = c - r * 528;
    int j = cc >> 3;
    int ci = (cc & 7) << 3;
    *(ushort8*)&As[(r * 66 + j) * AS_STRIDE + ci] = v;
  }

  floatx4 acc[4][4] = {};

  const int row_sel = wave >> 1;         // which of the 2 output rows
  const int nz0 = (wave & 1) << 2;       // fragment nz base (0 or 4)
  const __hip_bfloat16* bTile = kerF + (size_t)n_tile * 18 * 8 * 64 * 8;

  __syncthreads();  // A ready; no further barriers

  short8 aCur[4], aNxt[4], b0[4], b1[4], b2[4];

  auto loadB = [&](short8* dst, int ks) {
#pragma unroll
    for (int ni = 0; ni < 4; ++ni)
      dst[ni] = *(const short8*)(bTile + ((size_t)(ks * 8 + nz0 + ni) * 64 + lane) * 8);
  };
  auto loadA = [&](short8* dst, int ks) {
    const int tap = ks >> 1, khalf = ks & 1;
    const int kh = tap / 3, kw = tap - kh * 3;
    const __hip_bfloat16* aBase =
        As + ((row_sel + kh) * 66 + kw + lane15) * AS_STRIDE + quad * 8 + khalf * 32;
#pragma unroll
    for (int mi = 0; mi < 4; ++mi)
      dst[mi] = *(const short8*)(aBase + mi * 16 * AS_STRIDE);
  };

  loadB(b0, 0);
  loadB(b1, 1);
  loadA(aCur, 0);
#pragma unroll
  for (int ks = 0; ks < 18; ++ks) {
    if (ks + 2 < 18) loadB(b2, ks + 2);
    if (ks + 1 < 18) loadA(aNxt, ks + 1);
#pragma unroll
    for (int mi = 0; mi < 4; ++mi)
#pragma unroll
      for (int ni = 0; ni < 4; ++ni)
        acc[mi][ni] = __builtin_amdgcn_mfma_f32_16x16x32_bf16(
            aCur[mi], b0[ni], acc[mi][ni], 0, 0, 0);
#pragma unroll
    for (int r = 0; r < 4; ++r) {
      aCur[r] = aNxt[r];
      b0[r] = b1[r];
      b1[r] = b2[r];
    }
  }

  // ---- Epilogue: ELU + store. D layout: row=quad*4+reg, col=lane15 ----
  const int h = h0 + row_sel;
  float* outp = out + (size_t)((b * 64 + h) * 64) * 1024 +
                (size_t)(n_tile * 128 + (nz0 << 4) + lane15);
#pragma unroll
  for (int mi = 0; mi < 4; ++mi) {
#pragma unroll
    for (int r = 0; r < 4; ++r) {
      int w = mi * 16 + quad * 4 + r;
      float* orow = outp + (size_t)w * 1024;
#pragma unroll
      for (int ni = 0; ni < 4; ++ni) {
        float v = acc[mi][ni][r];
        orow[ni * 16] = v > 0.f ? v : expm1f(v);
      }
    }
  }
}

extern "C" void kernel_launch(void* const* d_in, const int* in_sizes, int n_in,
                              void* d_out, int out_size, void* d_ws, size_t ws_size,
                              hipStream_t stream) {
  const float* x      = (const float*)d_in[0];
  const float* mu     = (const float*)d_in[1];
  const float* logstd = (const float*)d_in[2];
  const float* noise  = (const float*)d_in[3];
  float* out = (float*)d_out;
  __hip_bfloat16* kerF = (__hip_bfloat16*)d_ws;
  __hip_bfloat16* xpad = (__hip_bfloat16*)((char*)d_ws + KERF_BYTES);

  prep_k<<<2250, 256, 0, stream>>>(x, mu, logstd, noise, kerF, xpad);
  conv_elu_k<<<dim3(8, 512), 256, 0, stream>>>(xpad, kerF, out);
}